// Round 5
// baseline (127.889 us; speedup 1.0000x reference)
//
#include <hip/hip_runtime.h>
#include <hip/hip_bf16.h>

#define BATCH 16384
#define BT 8            // batch elements per block
#define NTHREADS 512    // 8 waves

// ---- workspace: bf16 weights, original layout (rows = output neuron, cols = k)
#define W1B_OFF 0                       // [128][64]
#define W2B_OFF (128*64)                // [128][128]
#define W3B_OFF (W2B_OFF + 128*128)     // [512][128]
#define WS_SHORTS (W3B_OFF + 512*128)   // 90112 shorts

// ---- LDS layout (bytes), phase overlays
#define SM_HB    0
#define SM_Z1    2304
#define SM_Z2    6656
#define SM_A2    11008
#define SM_DZ1   0
#define SM_PJ    0
#define SM_T     20224
#define SM_DZ2   20224
#define SM_VT    37632      // bf16 [8][64][8]  Vt[e][n][j] = V_j[n]
#define SM_S1T   45824      // bf16 [128][8]
#define SM_S2T   47872      // bf16 [128][8]
#define SM_SIG   49920      // f32  [8][36]
#define SM_TOTAL 51072

typedef __attribute__((ext_vector_type(8))) short bf16x8;
typedef __attribute__((ext_vector_type(4))) float f32x4;

__device__ __forceinline__ float bf2f(unsigned int u16) {
    unsigned int x = u16 << 16;
    float f; __builtin_memcpy(&f, &x, 4); return f;
}
__device__ __forceinline__ unsigned short f2bf(float f) {
    unsigned int x; __builtin_memcpy(&x, &f, 4);
    x = (x + 0x7FFFu + ((x >> 16) & 1u)) >> 16;
    return (unsigned short)x;
}
__device__ __forceinline__ void unpack8(uint4 q, float* f) {
    f[0] = bf2f(q.x & 0xFFFFu); f[1] = bf2f(q.x >> 16);
    f[2] = bf2f(q.y & 0xFFFFu); f[3] = bf2f(q.y >> 16);
    f[4] = bf2f(q.z & 0xFFFFu); f[5] = bf2f(q.z >> 16);
    f[6] = bf2f(q.w & 0xFFFFu); f[7] = bf2f(q.w >> 16);
}
__device__ __forceinline__ void sp_sig(float x, float& sp, float& sig) {
    float t = __expf(-fabsf(x));
    float r = __builtin_amdgcn_rcpf(1.f + t);
    sig = (x >= 0.f) ? r : 1.f - r;
    sp  = fmaxf(x, 0.f) + __logf(1.f + t);
}
__device__ __forceinline__ float tanh_fast(float x) {
    float t = __expf(-2.f * fabsf(x));
    float y = (1.f - t) * __builtin_amdgcn_rcpf(1.f + t);
    unsigned int xb, yb;
    __builtin_memcpy(&xb, &x, 4);
    __builtin_memcpy(&yb, &y, 4);
    yb |= (xb & 0x80000000u);
    float rr; __builtin_memcpy(&rr, &yb, 4);
    return rr;
}
__device__ __forceinline__ bf16x8 ldfrag(const unsigned short* p) {
    return *reinterpret_cast<const bf16x8*>(p);
}

__global__ void prep_weights(const float* __restrict__ W1,
                             const float* __restrict__ W2,
                             const float* __restrict__ W3,
                             unsigned short* __restrict__ wb) {
    int i = blockIdx.x * blockDim.x + threadIdx.x;
    if (i >= WS_SHORTS) return;
    float v;
    if (i < W2B_OFF) v = W1[i];
    else if (i < W3B_OFF) v = W2[i - W2B_OFF];
    else v = W3[i - W3B_OFF];
    wb[i] = f2bf(v);
}

__global__ __launch_bounds__(NTHREADS, 4)
void logncde_main(const float* __restrict__ hg,
                  const float* __restrict__ sigg,
                  const float* __restrict__ b1,
                  const float* __restrict__ b2,
                  const float* __restrict__ b3,
                  const unsigned short* __restrict__ wsb,
                  float* __restrict__ out) {
    __shared__ __align__(16) char sm[SM_TOTAL];
    unsigned short* hb  = (unsigned short*)(sm + SM_HB);   // [16][72]
    unsigned short* z1b = (unsigned short*)(sm + SM_Z1);   // [16][136]
    unsigned short* z2b = (unsigned short*)(sm + SM_Z2);   // [16][136]
    unsigned short* A2  = (unsigned short*)(sm + SM_A2);   // [64][72]
    unsigned short* s1t = (unsigned short*)(sm + SM_S1T);  // [128][8]
    unsigned short* s2t = (unsigned short*)(sm + SM_S2T);  // [128][8]
    unsigned short* Vt  = (unsigned short*)(sm + SM_VT);   // [8][64][8]
    float*          sigs= (float*)(sm + SM_SIG);           // [8][36]
    unsigned short* Tsm = (unsigned short*)(sm + SM_T);    // [64][72]
    unsigned short* dZ1 = (unsigned short*)(sm + SM_DZ1);  // [64][136]
    unsigned short* dZ2 = (unsigned short*)(sm + SM_DZ2);  // [64][136]
    float*          pj  = (float*)(sm + SM_PJ);            // [8][8][64]

    const int tid = threadIdx.x;
    const int b0 = blockIdx.x * BT;

    const int lane = tid & 63;
    const int w = tid >> 6;
    const int r16 = lane & 15;
    const int kb = lane >> 4;
    const int crow = (lane >> 4) * 4;

    // ---- phase 0: load h + signatures
    {
        int e = tid >> 6, k = tid & 63;
        hb[e * 72 + k] = f2bf(hg[(b0 + e) * 64 + k]);
    }
    if (tid < BT * 36) {
        int e = tid / 36, j = tid % 36;
        sigs[e * 36 + j] = sigg[(b0 + e) * 36 + j];
    }
    __syncthreads();

    // ---- A2 build: A2[m=j*8+e][kidx=e'*8+i] = (e'==e) ? c[i][j]_e : 0
    {
        int e = lane >> 3, kg = lane & 7, j = w;
        uint4 q = {0u, 0u, 0u, 0u};
        if (kg == e) {
            unsigned short c8[8];
            #pragma unroll
            for (int i = 0; i < 8; ++i) {
                float v = 0.f;
                if (i < j) {
                    int p = 7 * i - i * (i - 1) / 2 + (j - i - 1);
                    v = sigs[e * 36 + 8 + p];
                } else if (i > j) {
                    int p = 7 * j - j * (j - 1) / 2 + (i - j - 1);
                    v = -sigs[e * 36 + 8 + p];
                }
                c8[i] = f2bf(v);
            }
            q.x = (unsigned int)c8[0] | ((unsigned int)c8[1] << 16);
            q.y = (unsigned int)c8[2] | ((unsigned int)c8[3] << 16);
            q.z = (unsigned int)c8[4] | ((unsigned int)c8[5] << 16);
            q.w = (unsigned int)c8[6] | ((unsigned int)c8[7] << 16);
        }
        int m = j * 8 + e;
        *reinterpret_cast<uint4*>(&A2[m * 72 + kg * 8]) = q;
    }

    // ---- fwd1 (MFMA): a1[8][128] = h @ W1^T; prefetch both B frags
    {
        const unsigned short* Ab = hb + r16 * 72 + kb * 8;
        const unsigned short* Bb = wsb + W1B_OFF + (w * 16 + r16) * 64 + kb * 8;
        bf16x8 bfr[2], afr[2];
        #pragma unroll
        for (int ks = 0; ks < 2; ++ks) bfr[ks] = ldfrag(Bb + ks * 32);
        #pragma unroll
        for (int ks = 0; ks < 2; ++ks) afr[ks] = ldfrag(Ab + ks * 32);
        f32x4 acc = {};
        #pragma unroll
        for (int ks = 0; ks < 2; ++ks)
            acc = __builtin_amdgcn_mfma_f32_16x16x32_bf16(afr[ks], bfr[ks], acc, 0, 0, 0);
        if (lane < 32) {
            int col = w * 16 + r16;
            float bb = b1[col];
            unsigned short sp4[4];
            #pragma unroll
            for (int rr = 0; rr < 4; ++rr) {
                int e = crow + rr;
                float sp, sg;
                sp_sig(acc[rr] + bb, sp, sg);
                z1b[e * 136 + col] = f2bf(sp);
                sp4[rr] = f2bf(sg);
            }
            uint2 qq;
            qq.x = (unsigned int)sp4[0] | ((unsigned int)sp4[1] << 16);
            qq.y = (unsigned int)sp4[2] | ((unsigned int)sp4[3] << 16);
            *reinterpret_cast<uint2*>(&s1t[col * 8 + crow]) = qq;
        }
    }
    __syncthreads();

    // ---- fwd2 (MFMA): a2 = z1 @ W2^T; prefetch 4 B frags
    {
        const unsigned short* Ab = z1b + r16 * 136 + kb * 8;
        const unsigned short* Bb = wsb + W2B_OFF + (w * 16 + r16) * 128 + kb * 8;
        bf16x8 bfr[4], afr[4];
        #pragma unroll
        for (int ks = 0; ks < 4; ++ks) bfr[ks] = ldfrag(Bb + ks * 32);
        #pragma unroll
        for (int ks = 0; ks < 4; ++ks) afr[ks] = ldfrag(Ab + ks * 32);
        f32x4 acc = {};
        #pragma unroll
        for (int ks = 0; ks < 4; ++ks)
            acc = __builtin_amdgcn_mfma_f32_16x16x32_bf16(afr[ks], bfr[ks], acc, 0, 0, 0);
        if (lane < 32) {
            int col = w * 16 + r16;
            float bb = b2[col];
            unsigned short sp4[4];
            #pragma unroll
            for (int rr = 0; rr < 4; ++rr) {
                int e = crow + rr;
                float sp, sg;
                sp_sig(acc[rr] + bb, sp, sg);
                z2b[e * 136 + col] = f2bf(sp);
                sp4[rr] = f2bf(sg);
            }
            uint2 qq;
            qq.x = (unsigned int)sp4[0] | ((unsigned int)sp4[1] << 16);
            qq.y = (unsigned int)sp4[2] | ((unsigned int)sp4[3] << 16);
            *reinterpret_cast<uint2*>(&s2t[col * 8 + crow]) = qq;
        }
    }
    __syncthreads();

    // ---- fwd3 (MFMA): V = tanh(z2 @ W3^T + b3); prefetch all 16 B frags
    {
        const unsigned short* Ab = z2b + r16 * 136 + kb * 8;
        const unsigned short* Bb = wsb + W3B_OFF + kb * 8;
        bf16x8 bfr[16], afr[4];
        #pragma unroll
        for (int nt = 0; nt < 4; ++nt)
            #pragma unroll
            for (int ks = 0; ks < 4; ++ks)
                bfr[nt * 4 + ks] = ldfrag(Bb + (w * 64 + nt * 16 + r16) * 128 + ks * 32);
        #pragma unroll
        for (int ks = 0; ks < 4; ++ks) afr[ks] = ldfrag(Ab + ks * 32);
        f32x4 acc[4] = {};
        #pragma unroll
        for (int nt = 0; nt < 4; ++nt)
            #pragma unroll
            for (int ks = 0; ks < 4; ++ks)
                acc[nt] = __builtin_amdgcn_mfma_f32_16x16x32_bf16(afr[ks], bfr[nt * 4 + ks], acc[nt], 0, 0, 0);
        if (lane < 32) {
            #pragma unroll
            for (int nt = 0; nt < 4; ++nt) {
                int c = w * 64 + nt * 16 + r16;
                float bb = b3[c];
                int n = c & 63;
                #pragma unroll
                for (int rr = 0; rr < 4; ++rr) {
                    int e = crow + rr;
                    Vt[(e * 64 + n) * 8 + w] = f2bf(tanh_fast(acc[nt][rr] + bb));
                }
            }
        }
    }
    __syncthreads();

    // ---- T-build (MFMA): T[64][64] = A2 @ Vt-as-B; all frags from LDS, prefetch
    {
        int mt = w & 3, nh = w >> 2;
        const unsigned short* Ab = A2 + (mt * 16 + r16) * 72 + kb * 8;
        bf16x8 afr[2], bfr[2][2];
        #pragma unroll
        for (int ks = 0; ks < 2; ++ks) {
            afr[ks] = ldfrag(Ab + ks * 32);
            int ep = ks * 4 + kb;
            #pragma unroll
            for (int nt = 0; nt < 2; ++nt) {
                int n = nh * 32 + nt * 16 + r16;
                bfr[ks][nt] = ldfrag(&Vt[(ep * 64 + n) * 8]);
            }
        }
        f32x4 acc[2] = {};
        #pragma unroll
        for (int ks = 0; ks < 2; ++ks)
            #pragma unroll
            for (int nt = 0; nt < 2; ++nt)
                acc[nt] = __builtin_amdgcn_mfma_f32_16x16x32_bf16(afr[ks], bfr[ks][nt], acc[nt], 0, 0, 0);
        #pragma unroll
        for (int nt = 0; nt < 2; ++nt) {
            int col = nh * 32 + nt * 16 + r16;
            #pragma unroll
            for (int rr = 0; rr < 4; ++rr) {
                int row = mt * 16 + crow + rr;
                Tsm[row * 72 + col] = f2bf(acc[nt][rr]);
            }
        }
    }
    __syncthreads();

    // ---- jvp1 (MFMA): dA1 = T @ W1^T; prefetch all 8 B frags; mask s1 -> dZ1
    {
        int mt = w & 3, nh = w >> 2;
        const unsigned short* Ab = Tsm + (mt * 16 + r16) * 72 + kb * 8;
        const unsigned short* Bb = wsb + W1B_OFF + kb * 8;
        bf16x8 bfr[8], afr[2];
        #pragma unroll
        for (int nt = 0; nt < 4; ++nt)
            #pragma unroll
            for (int ks = 0; ks < 2; ++ks)
                bfr[nt * 2 + ks] = ldfrag(Bb + (nh * 64 + nt * 16 + r16) * 64 + ks * 32);
        #pragma unroll
        for (int ks = 0; ks < 2; ++ks) afr[ks] = ldfrag(Ab + ks * 32);
        f32x4 acc[4] = {};
        #pragma unroll
        for (int nt = 0; nt < 4; ++nt)
            #pragma unroll
            for (int ks = 0; ks < 2; ++ks)
                acc[nt] = __builtin_amdgcn_mfma_f32_16x16x32_bf16(afr[ks], bfr[nt * 2 + ks], acc[nt], 0, 0, 0);
        int ebase = crow & 7;
        #pragma unroll
        for (int nt = 0; nt < 4; ++nt) {
            int col = nh * 64 + nt * 16 + r16;
            uint2 qq = *reinterpret_cast<const uint2*>(&s1t[col * 8 + ebase]);
            float s4[4];
            s4[0] = bf2f(qq.x & 0xFFFFu); s4[1] = bf2f(qq.x >> 16);
            s4[2] = bf2f(qq.y & 0xFFFFu); s4[3] = bf2f(qq.y >> 16);
            #pragma unroll
            for (int rr = 0; rr < 4; ++rr) {
                int row = mt * 16 + crow + rr;
                dZ1[row * 136 + col] = f2bf(acc[nt][rr] * s4[rr]);
            }
        }
    }
    __syncthreads();

    // ---- jvp2 (MFMA): dA2 = dZ1 @ W2^T; prefetch all 16 B frags; mask s2 -> dZ2
    {
        int mt = w & 3, nh = w >> 2;
        const unsigned short* Ab = dZ1 + (mt * 16 + r16) * 136 + kb * 8;
        const unsigned short* Bb = wsb + W2B_OFF + kb * 8;
        bf16x8 bfr[16], afr[4];
        #pragma unroll
        for (int nt = 0; nt < 4; ++nt)
            #pragma unroll
            for (int ks = 0; ks < 4; ++ks)
                bfr[nt * 4 + ks] = ldfrag(Bb + (nh * 64 + nt * 16 + r16) * 128 + ks * 32);
        #pragma unroll
        for (int ks = 0; ks < 4; ++ks) afr[ks] = ldfrag(Ab + ks * 32);
        f32x4 acc[4] = {};
        #pragma unroll
        for (int nt = 0; nt < 4; ++nt)
            #pragma unroll
            for (int ks = 0; ks < 4; ++ks)
                acc[nt] = __builtin_amdgcn_mfma_f32_16x16x32_bf16(afr[ks], bfr[nt * 4 + ks], acc[nt], 0, 0, 0);
        int ebase = crow & 7;
        #pragma unroll
        for (int nt = 0; nt < 4; ++nt) {
            int col = nh * 64 + nt * 16 + r16;
            uint2 qq = *reinterpret_cast<const uint2*>(&s2t[col * 8 + ebase]);
            float s4[4];
            s4[0] = bf2f(qq.x & 0xFFFFu); s4[1] = bf2f(qq.x >> 16);
            s4[2] = bf2f(qq.y & 0xFFFFu); s4[3] = bf2f(qq.y >> 16);
            #pragma unroll
            for (int rr = 0; rr < 4; ++rr) {
                int row = mt * 16 + crow + rr;
                dZ2[row * 136 + col] = f2bf(acc[nt][rr] * s4[rr]);
            }
        }
    }
    __syncthreads();

    // ---- jvp3 (MFMA): wave w = field j; prefetch all 16 B frags; mask tanh' -> pj
    {
        int j = w;
        int mt = j >> 1, half = j & 1;
        const unsigned short* Ab = dZ2 + (mt * 16 + r16) * 136 + kb * 8;
        const unsigned short* Bb = wsb + W3B_OFF + (j * 64) * 128 + kb * 8;
        bf16x8 bfr[16], afr[4];
        #pragma unroll
        for (int nt = 0; nt < 4; ++nt)
            #pragma unroll
            for (int ks = 0; ks < 4; ++ks)
                bfr[nt * 4 + ks] = ldfrag(Bb + (nt * 16 + r16) * 128 + ks * 32);
        #pragma unroll
        for (int ks = 0; ks < 4; ++ks) afr[ks] = ldfrag(Ab + ks * 32);
        f32x4 acc[4] = {};
        #pragma unroll
        for (int nt = 0; nt < 4; ++nt)
            #pragma unroll
            for (int ks = 0; ks < 4; ++ks)
                acc[nt] = __builtin_amdgcn_mfma_f32_16x16x32_bf16(afr[ks], bfr[nt * 4 + ks], acc[nt], 0, 0, 0);
        if ((crow >> 3) == half) {
            #pragma unroll
            for (int nt = 0; nt < 4; ++nt) {
                int np = nt * 16 + r16;
                #pragma unroll
                for (int rr = 0; rr < 4; ++rr) {
                    int e = (crow + rr) & 7;
                    float v = bf2f(Vt[(e * 64 + np) * 8 + j]);
                    pj[(j * 8 + e) * 64 + np] = (1.f - v * v) * acc[nt][rr];
                }
            }
        }
    }
    __syncthreads();

    // ---- reduce
    {
        int e = tid >> 6, np = tid & 63;
        uint4 q = *reinterpret_cast<const uint4*>(&Vt[(e * 64 + np) * 8]);
        float v8[8]; unpack8(q, v8);
        float s = 0.f;
        #pragma unroll
        for (int j = 0; j < 8; ++j) s += pj[(j * 8 + e) * 64 + np];
        float l1 = 0.f;
        #pragma unroll
        for (int i = 0; i < 8; ++i) l1 += sigs[e * 36 + i] * v8[i];
        out[(b0 + e) * 64 + np] = l1 + s;
    }
}

extern "C" void kernel_launch(void* const* d_in, const int* in_sizes, int n_in,
                              void* d_out, int out_size, void* d_ws, size_t ws_size,
                              hipStream_t stream) {
    const float* hg  = (const float*)d_in[0];
    const float* sg  = (const float*)d_in[1];
    const float* W1  = (const float*)d_in[2];
    const float* b1  = (const float*)d_in[3];
    const float* W2  = (const float*)d_in[4];
    const float* b2  = (const float*)d_in[5];
    const float* W3  = (const float*)d_in[6];
    const float* b3  = (const float*)d_in[7];
    float* outp = (float*)d_out;
    unsigned short* wsb = (unsigned short*)d_ws;

    hipLaunchKernelGGL(prep_weights, dim3((WS_SHORTS + 255) / 256), dim3(256), 0, stream,
                       W1, W2, W3, wsb);
    hipLaunchKernelGGL(logncde_main, dim3(BATCH / BT), dim3(NTHREADS), 0, stream,
                       hg, sg, b1, b2, b3, wsb, outp);
}